// Round 5
// baseline (15676.917 us; speedup 1.0000x reference)
//
#include <hip/hip_runtime.h>
#include <cstdint>
#include <cstddef>

// Problem constants
#define BB 32
#define TT 1024
#define DD 512
#define HH 512
#define NBLK 128           // persistent blocks: 64 per direction, 8 cols each

typedef __bf16 bf16x8 __attribute__((ext_vector_type(8)));
typedef float  f32x4  __attribute__((ext_vector_type(4)));
typedef unsigned long long u64;

// ws layout (bytes):
//   hfrag : ushort[2 dir][2 buf][2 ntile][16 s][64 lane][8] = 131072 B @ 0
//   xhat  : float [2 pass][TT][BB]  (plain, epilogue only)   = 262144 B @ 131072
//   xs    : u64   [TT][BB]  stamped x_hat stream, write-once = 262144 B @ 393216
//   flags : int   [NBLK]  (dir0: 0..63, dir1: 64..127)       =    512 B @ 655360
#define HFRAG_OFF 0
#define XHAT_OFF  131072
#define XS_OFF    393216
#define FLAGS_OFF 655360

#define AT_LOAD(p)     __hip_atomic_load((p),      __ATOMIC_RELAXED, __HIP_MEMORY_SCOPE_AGENT)
#define AT_STORE(p, v) __hip_atomic_store((p), (v), __ATOMIC_RELAXED, __HIP_MEMORY_SCOPE_AGENT)

__device__ __forceinline__ float sigm(float x) {
    return 1.f / (1.f + __expf(-x));
}
__device__ __forceinline__ float tanh_fast(float x) {
    x = fminf(15.f, fmaxf(-15.f, x));
    float e = __expf(2.f * x);
    return (e - 1.f) / (e + 1.f);
}

// ---- per-direction barrier --------------------------------------------
// Arrival: ONE relaxed sc1 store of the monotone round counter (no RMW).
// Ordering data->flag is by completion: s_waitcnt(0) drains this block's h/x
// stores before the flag store issues. Wait: poll own direction's 64 flags
// (4 cachelines) with signed '>=' (0xAAAAAAAA ws-poison is negative, so
// un-started blocks read "not yet"; monotone+'>=' gives liveness), with
// s_sleep backoff to keep poll traffic off the arrival path.
__device__ __forceinline__ void barrier_arrive(int* flags, int bid, int n) {
    __builtin_amdgcn_s_waitcnt(0);
    __syncthreads();
    if (threadIdx.x == 0) AT_STORE(&flags[bid], n);
}
__device__ __forceinline__ void barrier_wait(const int* flags, int dir, int n) {
    if (threadIdx.x < 64) {
        const u64* f64 = (const u64*)(flags + (dir << 6));
        const int i = threadIdx.x & 31;          // 32 u64 cover 64 flags
        for (;;) {
            u64 a = AT_LOAD(&f64[i]);
            bool ok = ((int)a >= n) & ((int)(a >> 32) >= n);
            if (__all(ok)) break;
            __builtin_amdgcn_s_sleep(1);
        }
    }
    __syncthreads();
}

__global__ __launch_bounds__(256, 1) void lstm_persistent(
    const float* __restrict__ u,
    const float* __restrict__ wih_f, const float* __restrict__ whh_f,
    const float* __restrict__ bih_f, const float* __restrict__ bhh_f,
    const float* __restrict__ wih_b, const float* __restrict__ whh_b,
    const float* __restrict__ bih_b, const float* __restrict__ bhh_b,
    unsigned short* __restrict__ hfrag, float* __restrict__ xhat,
    u64* __restrict__ xs, int* __restrict__ flags)
{
    const int bid  = blockIdx.x;
    const int dir  = bid >> 6;        // 0 = forward cell, 1 = backward cell
    const int kb   = bid & 63;
    const int k0   = kb << 3;         // 8 hidden columns per block
    const int tid  = threadIdx.x;
    const int wid  = tid >> 6;        // 4 waves: (mi = wid>>1, ni = wid&1)
    const int mi   = wid >> 1;        // col-group half (4 cols each)
    const int ni   = wid & 1;         // batch half (16 batches each)
    const int lane = tid & 63;
    const int quad = lane >> 4;
    const int l16  = lane & 15;

    const float* wih = dir ? wih_b : wih_f;
    const float* whh = dir ? whh_b : whh_f;
    const float* bih = dir ? bih_b : bih_f;
    const float* bhh = dir ? bhh_b : bhh_f;

    // ---- A-fragments (weights) pinned in registers for the whole kernel ----
    // A-frag layout: lane holds A[m = lane&15][k = quad*8 + i], i = 0..7
    // wave's M rows: m -> global gate row j = (m>>2)*HH + (k0 + 4*mi) + (m&3)
    bf16x8 wihF[16], whhF[16];
    {
        const int jg = (l16 >> 2) * HH + (k0 + 4 * mi) + (l16 & 3);
        #pragma unroll
        for (int s = 0; s < 16; ++s) {
            const float* p = wih + (size_t)jg * DD + s * 32 + quad * 8;
            const float* q = whh + (size_t)jg * HH + s * 32 + quad * 8;
            bf16x8 a, b;
            #pragma unroll
            for (int i = 0; i < 8; ++i) { a[i] = (__bf16)p[i]; b[i] = (__bf16)q[i]; }
            wihF[s] = a;
            whhF[s] = b;
        }
    }

    // ---- per-lane cell: (kc = k0 + 4*mi + quad, bc = ni*16 + l16) ----
    const int kc = k0 + 4 * mi + quad;
    const int bc = ni * 16 + l16;

    // rowsum(W_ih) from the frags (bf16-rounded terms == what the MFMA uses)
    float rsv[4], biasv[4];
    {
        float rs = 0.f;
        #pragma unroll
        for (int s = 0; s < 16; ++s)
            #pragma unroll
            for (int i = 0; i < 8; ++i) rs += (float)wihF[s][i];
        rs += __shfl_xor(rs, 16);
        rs += __shfl_xor(rs, 32);      // lane l16 holds rowsum of wave row l16
        #pragma unroll
        for (int g = 0; g < 4; ++g) {
            rsv[g]   = __shfl(rs, g * 4 + quad);   // row j = g*HH + kc
            const int j = g * HH + kc;
            biasv[g] = bih[j] + bhh[j];
        }
    }

    // ---- h slot addressing (B-fragment layout position for (m=kc, n=bc)) ----
    // ushort idx = ((((dir*2+buf)*2+ni)*16 + s)*64 + lane)*8 + i
    const int sw = kc >> 5, qw = (kc >> 3) & 3, iw = kc & 7;
    const int lanew = qw * 16 + l16;
    unsigned* hfrag32 = (unsigned*)hfrag;
    const int ws32_0 = (((((dir * 2 + 0) * 2 + ni) * 16 + sw) * 64 + lanew) * 8 + iw) >> 1;
    const int ws32_1 = ws32_0 + (2 * 16 * 64 * 8 >> 1);
    const u64* h64 = (const u64*)hfrag;
    const int rbA = ((dir * 2 + 0) * 2 + ni) * 2048 + lane * 2;   // buf0, u64 units
    const int rbB = ((dir * 2 + 1) * 2 + ni) * 2048 + lane * 2;   // buf1

    // zero-init h buffer 0 (quad-even lanes of all waves cover all packed pairs)
    if (!(quad & 1)) AT_STORE(&hfrag32[ws32_0], 0u);

    __shared__ __align__(16) float gbuf[4][16][20];  // wave-private gate transpose

    // input-side GEMM on u_t (plain cached loads; overlapped with barrier settle)
    auto ugemm = [&](int t) -> f32x4 {
        f32x4 a0 = (f32x4){0.f, 0.f, 0.f, 0.f};
        f32x4 a1 = (f32x4){0.f, 0.f, 0.f, 0.f};
        const float* ub = u + (size_t)bc * (TT * DD) + (size_t)t * DD + quad * 8;
        #pragma unroll
        for (int s = 0; s < 16; ++s) {
            const float4* p = (const float4*)(ub + s * 32);
            float4 x0 = p[0], x1 = p[1];
            bf16x8 uf;
            uf[0] = (__bf16)x0.x; uf[1] = (__bf16)x0.y;
            uf[2] = (__bf16)x0.z; uf[3] = (__bf16)x0.w;
            uf[4] = (__bf16)x1.x; uf[5] = (__bf16)x1.y;
            uf[6] = (__bf16)x1.z; uf[7] = (__bf16)x1.w;
            if (s & 1) a1 = __builtin_amdgcn_mfma_f32_16x16x32_bf16(wihF[s], uf, a1, 0, 0, 0);
            else       a0 = __builtin_amdgcn_mfma_f32_16x16x32_bf16(wihF[s], uf, a0, 0, 0, 0);
        }
        return a0 + a1;
    };

    // Round 1 doubles as the init barrier: arrival orders the h0 zero-stores.
    barrier_arrive(flags, bid, 1);
    f32x4 gih = ugemm(0);          // t=0 input GEMM hides in the init settle
    barrier_wait(flags, dir, 1);

    float c = 0.f;
    f32x4 gnext = gih;
    int n = 2;                      // next barrier round number

    for (int t = 0; t < TT; ++t) {
        #pragma unroll 1
        for (int pass = 0; pass < 2; ++pass, ++n) {
            const int bufR = (t * 2 + pass) & 1;

            // recurrent GEMM: prefetch all B-fragments (sc1 -> LLC), then MFMA
            u64 ha[16], hb[16];
            {
                const int rb = bufR ? rbB : rbA;
                #pragma unroll
                for (int s = 0; s < 16; ++s) {
                    ha[s] = AT_LOAD(&h64[rb + s * 128]);
                    hb[s] = AT_LOAD(&h64[rb + s * 128 + 1]);
                }
            }
            f32x4 acc0 = gih;
            f32x4 acc1 = (f32x4){0.f, 0.f, 0.f, 0.f};
            #pragma unroll
            for (int s = 0; s < 16; ++s) {
                union { u64 q[2]; bf16x8 v; } cvt;
                cvt.q[0] = ha[s]; cvt.q[1] = hb[s];
                if (s & 1) acc1 = __builtin_amdgcn_mfma_f32_16x16x32_bf16(whhF[s], cvt.v, acc1, 0, 0, 0);
                else       acc0 = __builtin_amdgcn_mfma_f32_16x16x32_bf16(whhF[s], cvt.v, acc0, 0, 0, 0);
            }
            f32x4 acc = acc0 + acc1;

            // pass-1 scalar feedback: poll the write-once stamped x_hat stream.
            // dir1: ordered by own barrier (already there). dir0: producer wrote
            // it before its pass-0 arrival — normally satisfied on first load.
            float xc = 0.f;
            if (pass) {
                u64 v = AT_LOAD(&xs[t * BB + bc]);
                while ((int)(v >> 32) < 1) {
                    __builtin_amdgcn_s_sleep(1);
                    v = AT_LOAD(&xs[t * BB + bc]);
                }
                xc = __builtin_bit_cast(float, (unsigned)v);
            }

            // D-layout -> per-cell gates via wave-private LDS
            float4 gw; gw.x = acc[0]; gw.y = acc[1]; gw.z = acc[2]; gw.w = acc[3];
            *(float4*)&gbuf[wid][l16][quad * 4] = gw;
            __syncthreads();
            float gI = gbuf[wid][l16][ 0 + quad] + biasv[0] + xc * rsv[0];
            float gF = gbuf[wid][l16][ 4 + quad] + biasv[1] + xc * rsv[1];
            float gG = gbuf[wid][l16][ 8 + quad] + biasv[2] + xc * rsv[2];
            float gO = gbuf[wid][l16][12 + quad] + biasv[3] + xc * rsv[3];

            float ig = sigm(gI), fg = sigm(gF), gg = tanh_fast(gG), og = sigm(gO);
            c = fg * c + ig * gg;
            float h = og * tanh_fast(c);

            // publish h: pack 2 bf16 (quad pair) -> one u32 sc1 store into buf 1-bufR
            float hp = __shfl_xor(h, 16);
            if (dir == 1 && kc == (HH - 1)) {
                AT_STORE(&xhat[pass * (TT * BB) + t * BB + bc], h);  // epilogue copy
                if (pass == 0)   // stamped feedback stream (write-once per (t,b))
                    AT_STORE(&xs[t * BB + bc],
                             ((u64)1u << 32) | (u64)__builtin_bit_cast(unsigned, h));
            }
            if (!(quad & 1)) {
                unsigned lo = (unsigned)__builtin_bit_cast(unsigned short, (__bf16)h);
                unsigned hi = (unsigned)__builtin_bit_cast(unsigned short, (__bf16)hp);
                AT_STORE(&hfrag32[bufR ? ws32_0 : ws32_1], lo | (hi << 16));
            }

            barrier_arrive(flags, bid, n);
            if (pass == 1 && t + 1 < TT)
                gnext = ugemm(t + 1);     // next timestep's input GEMM hides here
            barrier_wait(flags, dir, n);
        }
        gih = gnext;
    }
}

__global__ void epilogue(const float* __restrict__ u, const float* __restrict__ xhat,
                         float* __restrict__ out)
{
    const int i = blockIdx.x * blockDim.x + threadIdx.x;   // over float4 groups
    const float4 uv = ((const float4*)u)[i];
    const int bt = i >> 7;             // 128 float4 per (b,t)
    const int t = bt & (TT - 1);
    const int b = bt >> 10;
    const float s = 0.5f * (xhat[t * BB + b] + xhat[TT * BB + t * BB + b]);
    float4 o;
    o.x = 1.5f * uv.x + s;
    o.y = 1.5f * uv.y + s;
    o.z = 1.5f * uv.z + s;
    o.w = 1.5f * uv.w + s;
    ((float4*)out)[i] = o;
}

extern "C" void kernel_launch(void* const* d_in, const int* in_sizes, int n_in,
                              void* d_out, int out_size, void* d_ws, size_t ws_size,
                              hipStream_t stream) {
    const float* u     = (const float*)d_in[0];
    const float* wih_f = (const float*)d_in[1];
    const float* whh_f = (const float*)d_in[2];
    const float* bih_f = (const float*)d_in[3];
    const float* bhh_f = (const float*)d_in[4];
    const float* wih_b = (const float*)d_in[5];
    const float* whh_b = (const float*)d_in[6];
    const float* bih_b = (const float*)d_in[7];
    const float* bhh_b = (const float*)d_in[8];

    char* ws = (char*)d_ws;
    unsigned short* hfrag = (unsigned short*)(ws + HFRAG_OFF);
    float* xhat           = (float*)(ws + XHAT_OFF);
    u64* xs               = (u64*)(ws + XS_OFF);
    int* flags            = (int*)(ws + FLAGS_OFF);

    lstm_persistent<<<NBLK, 256, 0, stream>>>(
        u, wih_f, whh_f, bih_f, bhh_f, wih_b, whh_b, bih_b, bhh_b,
        hfrag, xhat, xs, flags);

    const int n4 = BB * TT * DD / 4;
    epilogue<<<n4 / 256, 256, 0, stream>>>(u, xhat, (float*)d_out);
}